// Round 3
// baseline (972.088 us; speedup 1.0000x reference)
//
#include <hip/hip_runtime.h>
#include <math.h>

#define BSZ 32
#define NP  1024

// ---- workspace layout (float offsets) ----
#define OFF_ACC    0                       // acc[0]=sum(logR - S); acc[1]=sum S;
                                           // acc[2]=sum T*logC; acc[3]=corr; acc[4]=chamfer
#define OFF_COS    8                       // dot[32], n1[32], n2[32]
#define OFF_COLC1  104
#define OFF_COLT1  (OFF_COLC1 + 32768)
#define OFF_COLC2  (OFF_COLC1 + 65536)
#define OFF_COLT2  (OFF_COLC1 + 98304)
#define ZERO_FLOATS (OFF_COLC1 + 131072)   // 131176 floats zeroed
#define OFF_POSE   ZERO_FLOATS             // 24 floats per batch (768)
#define OFF_P1TO2  (OFF_POSE + 768)        // float4 per point: 131072 floats
#define OFF_P2TO1  (OFF_P1TO2 + 131072)
#define OFF_P1IN2  (OFF_P2TO1 + 131072)
#define OFF_P2IN1  (OFF_P1IN2 + 131072)

__device__ __forceinline__ unsigned int pkbf(float lo, float hi) {
    return (__float_as_uint(lo) >> 16) | (__float_as_uint(hi) & 0xffff0000u);
}
__device__ __forceinline__ float bflo(unsigned int p) { return __uint_as_float(p << 16); }
__device__ __forceinline__ float bfhi(unsigned int p) { return __uint_as_float(p & 0xffff0000u); }

// ---------------- pose: sRt and its inverse (adjugate) ----------------
__global__ void k_pose(const float* __restrict__ scale,
                       const float* __restrict__ rot,
                       const float* __restrict__ tr,
                       float* __restrict__ pose) {
    int b = threadIdx.x;
    if (b >= BSZ) return;
    float s = scale[b];
    float M[9];
#pragma unroll
    for (int i = 0; i < 9; ++i) M[i] = rot[b * 9 + i] * s;
    float t0 = tr[b * 3 + 0], t1 = tr[b * 3 + 1], t2 = tr[b * 3 + 2];
    float det = M[0] * (M[4] * M[8] - M[5] * M[7])
              - M[1] * (M[3] * M[8] - M[5] * M[6])
              + M[2] * (M[3] * M[7] - M[4] * M[6]);
    float id = 1.0f / det;
    float inv[9];
    inv[0] =  (M[4] * M[8] - M[5] * M[7]) * id;
    inv[1] = -(M[1] * M[8] - M[2] * M[7]) * id;
    inv[2] =  (M[1] * M[5] - M[2] * M[4]) * id;
    inv[3] = -(M[3] * M[8] - M[5] * M[6]) * id;
    inv[4] =  (M[0] * M[8] - M[2] * M[6]) * id;
    inv[5] = -(M[0] * M[5] - M[2] * M[3]) * id;
    inv[6] =  (M[3] * M[7] - M[4] * M[6]) * id;
    inv[7] = -(M[0] * M[7] - M[1] * M[6]) * id;
    inv[8] =  (M[0] * M[4] - M[1] * M[3]) * id;
    float u0 = -(inv[0] * t0 + inv[1] * t1 + inv[2] * t2);
    float u1 = -(inv[3] * t0 + inv[4] * t1 + inv[5] * t2);
    float u2 = -(inv[6] * t0 + inv[7] * t1 + inv[8] * t2);
    float* P = pose + b * 24;
#pragma unroll
    for (int i = 0; i < 9; ++i) P[i] = M[i];
    P[9] = t0; P[10] = t1; P[11] = t2;
#pragma unroll
    for (int i = 0; i < 9; ++i) P[12 + i] = inv[i];
    P[21] = u0; P[22] = u1; P[23] = u2;
}

// ---------------- transform; store (x,y,z,|p|^2) float4 ----------------
__global__ void k_transform(const float* __restrict__ p1, const float* __restrict__ p2,
                            const float* __restrict__ pose,
                            float4* __restrict__ p1to2, float4* __restrict__ p2to1) {
    int idx = blockIdx.x * 256 + threadIdx.x;   // 32*1024
    int b = idx >> 10;
    const float* P = pose + b * 24;
    float x = p1[idx * 3 + 0], y = p1[idx * 3 + 1], z = p1[idx * 3 + 2];
    float o0 = P[0] * x + P[1] * y + P[2] * z + P[9];
    float o1 = P[3] * x + P[4] * y + P[5] * z + P[10];
    float o2 = P[6] * x + P[7] * y + P[8] * z + P[11];
    p1to2[idx] = make_float4(o0, o1, o2, o0 * o0 + o1 * o1 + o2 * o2);
    x = p2[idx * 3 + 0]; y = p2[idx * 3 + 1]; z = p2[idx * 3 + 2];
    o0 = P[12] * x + P[13] * y + P[14] * z + P[21];
    o1 = P[15] * x + P[16] * y + P[17] * z + P[22];
    o2 = P[18] * x + P[19] * y + P[20] * z + P[23];
    p2to1[idx] = make_float4(o0, o1, o2, o0 * o0 + o1 * o1 + o2 * o2);
}

// ---------------- the big fused pass over both assign matrices ----------------
// grid: 32 batches * 32 rowblocks = 1024 blocks, 256 threads (4 waves, 8 rows/wave)
// Column sums go to LDS via ds_add_f32 with a bank-swizzled, permutation-invariant
// layout: column c = 256*j + 4*ln + k  ->  idx = k*256 + 64*j + ln  (bank = ln%32, 2-way, free)
__global__ __launch_bounds__(256, 3) void k_big(
    const float* __restrict__ am1, const float* __restrict__ am2,
    const float* __restrict__ pts1, const float* __restrict__ pts2,
    float4* __restrict__ p1in2, float4* __restrict__ p2in1,
    float* __restrict__ colC1, float* __restrict__ colT1,
    float* __restrict__ colC2, float* __restrict__ colT2,
    float* __restrict__ cosacc, float* __restrict__ acc) {
    const int b  = blockIdx.x >> 5;
    const int rb = blockIdx.x & 31;
    const int wv = threadIdx.x >> 6;
    const int ln = threadIdx.x & 63;
    const int row0 = rb * 32 + wv * 8;

    __shared__ float cacc[4][NP];
    {
        float* cf = (float*)cacc;
#pragma unroll
        for (int i = 0; i < 16; ++i) cf[threadIdx.x + 256 * i] = 0.f;
    }
    __syncthreads();

    // lane's 16 fixed columns: c = 256*j + 4*ln + k; points packed to bf16 pairs (48 regs)
    unsigned int pax[4][2], pay[4][2], paz[4][2];
    unsigned int pbx[4][2], pby[4][2], pbz[4][2];
#pragma unroll
    for (int j = 0; j < 4; ++j) {
        int base = (b * NP + 256 * j + 4 * ln) * 3;
        float4 t0 = *(const float4*)(pts2 + base);
        float4 t1 = *(const float4*)(pts2 + base + 4);
        float4 t2 = *(const float4*)(pts2 + base + 8);
        pax[j][0] = pkbf(t0.x, t0.w); pax[j][1] = pkbf(t1.z, t2.y);
        pay[j][0] = pkbf(t0.y, t1.x); pay[j][1] = pkbf(t1.w, t2.z);
        paz[j][0] = pkbf(t0.z, t1.y); paz[j][1] = pkbf(t2.x, t2.w);
        t0 = *(const float4*)(pts1 + base);
        t1 = *(const float4*)(pts1 + base + 4);
        t2 = *(const float4*)(pts1 + base + 8);
        pbx[j][0] = pkbf(t0.x, t0.w); pbx[j][1] = pkbf(t1.z, t2.y);
        pby[j][0] = pkbf(t0.y, t1.x); pby[j][1] = pkbf(t1.w, t2.z);
        pbz[j][0] = pkbf(t0.z, t1.y); pbz[j][1] = pkbf(t2.x, t2.w);
    }

    float dacc = 0.f, n1a = 0.f, n2a = 0.f, e2a = 0.f, sSa = 0.f;

    const float4* rA = (const float4*)(am1 + ((size_t)b * NP + row0) * NP);
    const float4* rB = (const float4*)(am2 + ((size_t)b * NP + row0) * NP);

#pragma unroll 1
    for (int r = 0; r < 8; ++r) {
        float4 a[4], c4[4];
#pragma unroll
        for (int j = 0; j < 4; ++j) {
            a[j]  = rA[(size_t)r * 256 + ln + 64 * j];
            c4[j] = rB[(size_t)r * 256 + ln + 64 * j];
        }
        // cos-loss partials on raw values
#pragma unroll
        for (int j = 0; j < 4; ++j) {
            float4 a0 = a[j], c0 = c4[j];
            dacc = fmaf(a0.x, c0.x, fmaf(a0.y, c0.y, fmaf(a0.z, c0.z, fmaf(a0.w, c0.w, dacc))));
            n1a  = fmaf(a0.x, a0.x, fmaf(a0.y, a0.y, fmaf(a0.z, a0.z, fmaf(a0.w, a0.w, n1a))));
            n2a  = fmaf(c0.x, c0.x, fmaf(c0.y, c0.y, fmaf(c0.z, c0.z, fmaf(c0.w, c0.w, n2a))));
        }
        // ---- matrix 1 ----
        {
            float R = 0.f, Su = 0.f, qx = 0.f, qy = 0.f, qz = 0.f;
#pragma unroll
            for (int j = 0; j < 4; ++j) {
                float4 v = a[j];
                float e0 = __expf(v.x), e1 = __expf(v.y), e2 = __expf(v.z), e3 = __expf(v.w);
                R += (e0 + e1) + (e2 + e3);
                Su = fmaf(e0, v.x, Su); Su = fmaf(e1, v.y, Su);
                Su = fmaf(e2, v.z, Su); Su = fmaf(e3, v.w, Su);
                qx = fmaf(e0, bflo(pax[j][0]), qx); qx = fmaf(e1, bfhi(pax[j][0]), qx);
                qx = fmaf(e2, bflo(pax[j][1]), qx); qx = fmaf(e3, bfhi(pax[j][1]), qx);
                qy = fmaf(e0, bflo(pay[j][0]), qy); qy = fmaf(e1, bfhi(pay[j][0]), qy);
                qy = fmaf(e2, bflo(pay[j][1]), qy); qy = fmaf(e3, bfhi(pay[j][1]), qy);
                qz = fmaf(e0, bflo(paz[j][0]), qz); qz = fmaf(e1, bfhi(paz[j][0]), qz);
                qz = fmaf(e2, bflo(paz[j][1]), qz); qz = fmaf(e3, bfhi(paz[j][1]), qz);
                a[j] = make_float4(e0, e1, e2, e3);
            }
#pragma unroll
            for (int m = 1; m < 64; m <<= 1) {
                R  += __shfl_xor(R, m);  Su += __shfl_xor(Su, m);
                qx += __shfl_xor(qx, m); qy += __shfl_xor(qy, m); qz += __shfl_xor(qz, m);
            }
            float inv = 1.0f / R;
#pragma unroll
            for (int j = 0; j < 4; ++j) {
                float4 e = a[j];
                int i0 = 64 * j + ln;
                atomicAdd(&cacc[0][0 * 256 + i0], e.x); atomicAdd(&cacc[1][0 * 256 + i0], e.x * inv);
                atomicAdd(&cacc[0][1 * 256 + i0], e.y); atomicAdd(&cacc[1][1 * 256 + i0], e.y * inv);
                atomicAdd(&cacc[0][2 * 256 + i0], e.z); atomicAdd(&cacc[1][2 * 256 + i0], e.z * inv);
                atomicAdd(&cacc[0][3 * 256 + i0], e.w); atomicAdd(&cacc[1][3 * 256 + i0], e.w * inv);
            }
            float S = Su * inv;
            if (ln == 0) {
                e2a += __logf(R) - S;
                sSa += S;
                float o0 = qx * inv, o1 = qy * inv, o2 = qz * inv;
                p1in2[b * NP + row0 + r] = make_float4(o0, o1, o2, o0 * o0 + o1 * o1 + o2 * o2);
            }
        }
        // ---- matrix 2 ----
        {
            float R = 0.f, Su = 0.f, qx = 0.f, qy = 0.f, qz = 0.f;
#pragma unroll
            for (int j = 0; j < 4; ++j) {
                float4 v = c4[j];
                float e0 = __expf(v.x), e1 = __expf(v.y), e2 = __expf(v.z), e3 = __expf(v.w);
                R += (e0 + e1) + (e2 + e3);
                Su = fmaf(e0, v.x, Su); Su = fmaf(e1, v.y, Su);
                Su = fmaf(e2, v.z, Su); Su = fmaf(e3, v.w, Su);
                qx = fmaf(e0, bflo(pbx[j][0]), qx); qx = fmaf(e1, bfhi(pbx[j][0]), qx);
                qx = fmaf(e2, bflo(pbx[j][1]), qx); qx = fmaf(e3, bfhi(pbx[j][1]), qx);
                qy = fmaf(e0, bflo(pby[j][0]), qy); qy = fmaf(e1, bfhi(pby[j][0]), qy);
                qy = fmaf(e2, bflo(pby[j][1]), qy); qy = fmaf(e3, bfhi(pby[j][1]), qy);
                qz = fmaf(e0, bflo(pbz[j][0]), qz); qz = fmaf(e1, bfhi(pbz[j][0]), qz);
                qz = fmaf(e2, bflo(pbz[j][1]), qz); qz = fmaf(e3, bfhi(pbz[j][1]), qz);
                c4[j] = make_float4(e0, e1, e2, e3);
            }
#pragma unroll
            for (int m = 1; m < 64; m <<= 1) {
                R  += __shfl_xor(R, m);  Su += __shfl_xor(Su, m);
                qx += __shfl_xor(qx, m); qy += __shfl_xor(qy, m); qz += __shfl_xor(qz, m);
            }
            float inv = 1.0f / R;
#pragma unroll
            for (int j = 0; j < 4; ++j) {
                float4 e = c4[j];
                int i0 = 64 * j + ln;
                atomicAdd(&cacc[2][0 * 256 + i0], e.x); atomicAdd(&cacc[3][0 * 256 + i0], e.x * inv);
                atomicAdd(&cacc[2][1 * 256 + i0], e.y); atomicAdd(&cacc[3][1 * 256 + i0], e.y * inv);
                atomicAdd(&cacc[2][2 * 256 + i0], e.z); atomicAdd(&cacc[3][2 * 256 + i0], e.z * inv);
                atomicAdd(&cacc[2][3 * 256 + i0], e.w); atomicAdd(&cacc[3][3 * 256 + i0], e.w * inv);
            }
            float S = Su * inv;
            if (ln == 0) {
                e2a += __logf(R) - S;
                sSa += S;
                float o0 = qx * inv, o1 = qy * inv, o2 = qz * inv;
                p2in1[b * NP + row0 + r] = make_float4(o0, o1, o2, o0 * o0 + o1 * o1 + o2 * o2);
            }
        }
    }

    __syncthreads();
    // one coalesced global flush per block (same permuted layout; final reduction is
    // permutation-invariant since C and T share the layout)
#pragma unroll
    for (int qq = 0; qq < 4; ++qq) {
        int c = 256 * qq + threadIdx.x;
        atomicAdd(&colC1[b * NP + c], cacc[0][c]);
        atomicAdd(&colT1[b * NP + c], cacc[1][c]);
        atomicAdd(&colC2[b * NP + c], cacc[2][c]);
        atomicAdd(&colT2[b * NP + c], cacc[3][c]);
    }

#pragma unroll
    for (int m = 1; m < 64; m <<= 1) {
        dacc += __shfl_xor(dacc, m);
        n1a  += __shfl_xor(n1a, m);
        n2a  += __shfl_xor(n2a, m);
    }
    if (ln == 0) {
        atomicAdd(&cosacc[b], dacc);
        atomicAdd(&cosacc[32 + b], n1a);
        atomicAdd(&cosacc[64 + b], n2a);
        atomicAdd(&acc[0], e2a);
        atomicAdd(&acc[1], sSa);
    }
}

// ---------------- column finalize (T*logC) + correspondence loss ----------------
__global__ void k_tail(const float* __restrict__ colC1, const float* __restrict__ colT1,
                       const float* __restrict__ colC2, const float* __restrict__ colT2,
                       const float4* __restrict__ p1in2, const float4* __restrict__ p1to2,
                       const float4* __restrict__ p2in1, const float4* __restrict__ p2to1,
                       float* __restrict__ acc) {
    int idx = blockIdx.x * 256 + threadIdx.x;   // 65536
    float v;
    int i = idx;
    const float4* A; const float4* P;
    if (idx < 32768) {
        v = colT1[idx] * __logf(colC1[idx]);
        A = p1in2; P = p1to2;
    } else {
        int i2 = idx - 32768;
        v = colT2[i2] * __logf(colC2[i2]);
        A = p2in1; P = p2to1; i = i2;
    }
    float4 av = A[i], pv = P[i];
    float s = 0.f;
    float df;
    df = fabsf(av.x - pv.x); s += (df > 0.1f) ? (df - 0.05f) : (df * df * 5.0f);
    df = fabsf(av.y - pv.y); s += (df > 0.1f) ? (df - 0.05f) : (df * df * 5.0f);
    df = fabsf(av.z - pv.z); s += (df > 0.1f) ? (df - 0.05f) : (df * df * 5.0f);
#pragma unroll
    for (int m = 1; m < 64; m <<= 1) { v += __shfl_xor(v, m); s += __shfl_xor(s, m); }
    if ((threadIdx.x & 63) == 0) { atomicAdd(&acc[2], v); atomicAdd(&acc[3], s); }
}

// ---------------- chamfer: min|x-y|^2 = |x|^2 + min(|y|^2 - 2 x.y) ----------------
// grid 256 = pair(2)*dir(2)*b(32)*xhalf(2); block 256 thr (4 waves); X=2 pts/thread;
// each wave covers a quarter of the y cloud; partial mins combined in LDS.
__global__ __launch_bounds__(256) void k_chamfer(
    const float4* __restrict__ p1to2, const float4* __restrict__ p1in2,
    const float4* __restrict__ p2to1, const float4* __restrict__ p2in1,
    float* __restrict__ acc) {
    int blk   = blockIdx.x;
    int xhalf = blk & 1;
    int b     = (blk >> 1) & 31;
    int dir   = (blk >> 6) & 1;
    int pair  = blk >> 7;
    const float4* X; const float4* Y;
    if (pair == 0) { X = dir ? p1in2 : p1to2; Y = dir ? p1to2 : p1in2; }
    else           { X = dir ? p2in1 : p2to1; Y = dir ? p2to1 : p2in1; }
    __shared__ float4 ys[NP];
    __shared__ float mnbuf[4][512];
    int t = threadIdx.x;
    int wv = t >> 6;
#pragma unroll
    for (int i = 0; i < 4; ++i) ys[i * 256 + t] = Y[b * NP + i * 256 + t];
    __syncthreads();

    // this thread's 2 x-points
    float nx[2], ny[2], nz[2], xw[2];
#pragma unroll
    for (int k = 0; k < 2; ++k) {
        float4 xv = X[b * NP + xhalf * 512 + k * 256 + t];
        nx[k] = -2.0f * xv.x; ny[k] = -2.0f * xv.y; nz[k] = -2.0f * xv.z; xw[k] = xv.w;
    }
    float m0 = 3.0e38f, m1 = 3.0e38f;
    int y0 = wv * 256;
#pragma unroll 4
    for (int o = 0; o < 256; ++o) {
        float4 yv = ys[y0 + o];
        m0 = fminf(m0, fmaf(nx[0], yv.x, fmaf(ny[0], yv.y, fmaf(nz[0], yv.z, yv.w))));
        m1 = fminf(m1, fmaf(nx[1], yv.x, fmaf(ny[1], yv.y, fmaf(nz[1], yv.z, yv.w))));
    }
    int lt = t & 63;
    mnbuf[wv][0 * 256 + (wv * 64 + lt)] = 0.f; // placeholder to keep layout simple (overwritten)
    mnbuf[wv][lt + wv * 64] = 0.f;             // (unused slots harmless)
    __syncthreads();                            // ensure ys reads done before reuse? not needed; keep order
    mnbuf[wv][0 + (t & 255)] = m0;             // index t in [0,256)
    mnbuf[wv][256 + (t & 255)] = m1;
    __syncthreads();
    // wave wv finalizes x-chunk slice: combine 4 partial mins for slot s = wv*128.. hmm
    // simpler: thread t combines its own two slots across the 4 waves
    float f0 = fminf(fminf(mnbuf[0][t], mnbuf[1][t]), fminf(mnbuf[2][t], mnbuf[3][t]));
    float f1 = fminf(fminf(mnbuf[0][256 + t], mnbuf[1][256 + t]),
                     fminf(mnbuf[2][256 + t], mnbuf[3][256 + t]));
    float s = fmaxf(xw[0] + f0, 0.f) + fmaxf(xw[1] + f1, 0.f);
#pragma unroll
    for (int m = 1; m < 64; m <<= 1) s += __shfl_xor(s, m);
    if ((t & 63) == 0) atomicAdd(&acc[4], s);
}

// ---------------- finalize ----------------
__global__ void k_final(const float* __restrict__ acc, const float* __restrict__ cosacc,
                        float* __restrict__ out) {
    if (threadIdx.x != 0) return;
    const float invBN = 1.0f / 32768.0f;
    float ent2 = 1e-4f * acc[0] * invBN;
    float ent1 = 1e-4f * (acc[2] - acc[1]) * invBN;
    float corr = acc[3] * invBN;
    float cham = acc[4] * invBN;
    float cosl = 0.f;
    for (int b = 0; b < 32; ++b) {
        float dot = cosacc[b];
        float na = fmaxf(sqrtf(cosacc[32 + b]), 1e-8f);
        float nb = fmaxf(sqrtf(cosacc[64 + b]), 1e-8f);
        cosl += 1.0f - dot / (na * nb);
    }
    cosl *= (1.0f / 32.0f);
    out[0] = cham + corr + ent2 + ent1 + cosl;
}

extern "C" void kernel_launch(void* const* d_in, const int* in_sizes, int n_in,
                              void* d_out, int out_size, void* d_ws, size_t ws_size,
                              hipStream_t stream) {
    const float* p1    = (const float*)d_in[0];
    const float* p2    = (const float*)d_in[1];
    const float* am1   = (const float*)d_in[2];
    const float* am2   = (const float*)d_in[3];
    const float* scale = (const float*)d_in[4];
    const float* rot   = (const float*)d_in[5];
    const float* tr    = (const float*)d_in[6];

    float* ws = (float*)d_ws;
    float* acc    = ws + OFF_ACC;
    float* cosacc = ws + OFF_COS;
    float* colC1  = ws + OFF_COLC1;
    float* colT1  = ws + OFF_COLT1;
    float* colC2  = ws + OFF_COLC2;
    float* colT2  = ws + OFF_COLT2;
    float* pose   = ws + OFF_POSE;
    float4* p1to2 = (float4*)(ws + OFF_P1TO2);
    float4* p2to1 = (float4*)(ws + OFF_P2TO1);
    float4* p1in2 = (float4*)(ws + OFF_P1IN2);
    float4* p2in1 = (float4*)(ws + OFF_P2IN1);

    hipMemsetAsync(ws, 0, ZERO_FLOATS * sizeof(float), stream);

    k_pose<<<1, 64, 0, stream>>>(scale, rot, tr, pose);
    k_transform<<<128, 256, 0, stream>>>(p1, p2, pose, p1to2, p2to1);
    k_big<<<1024, 256, 0, stream>>>(am1, am2, p1, p2, p1in2, p2in1,
                                    colC1, colT1, colC2, colT2, cosacc, acc);
    k_tail<<<256, 256, 0, stream>>>(colC1, colT1, colC2, colT2,
                                    p1in2, p1to2, p2in1, p2to1, acc);
    k_chamfer<<<256, 256, 0, stream>>>(p1to2, p1in2, p2to1, p2in1, acc);
    k_final<<<1, 64, 0, stream>>>(acc, cosacc, (float*)d_out);
}

// Round 4
// 599.838 us; speedup vs baseline: 1.6206x; 1.6206x over previous
//
#include <hip/hip_runtime.h>
#include <math.h>

#define BSZ 32
#define NP  1024

// ---- workspace layout (float offsets) ----
#define OFF_ACC    0                       // acc[0]=sum(logR-S); acc[1]=sum S; acc[2]=sum T*logC;
                                           // acc[3]=corr; acc[4]=chamfer; acc[6]=ticket (uint)
#define OFF_COS    8                       // dot[32], n1[32], n2[32]
#define OFF_COLC1  104
#define OFF_COLT1  (OFF_COLC1 + 32768)
#define OFF_COLC2  (OFF_COLC1 + 65536)
#define OFF_COLT2  (OFF_COLC1 + 98304)
#define ZERO_FLOATS (OFF_COLC1 + 131072)   // 131176 floats zeroed (covers acc/cos/cols)
#define OFF_P1TO2  ZERO_FLOATS             // float4 per point: 131072 floats
#define OFF_P2TO1  (OFF_P1TO2 + 131072)
#define OFF_P1IN2  (OFF_P2TO1 + 131072)
#define OFF_P2IN1  (OFF_P1IN2 + 131072)

__device__ __forceinline__ unsigned int pkbf(float lo, float hi) {
    return (__float_as_uint(lo) >> 16) | (__float_as_uint(hi) & 0xffff0000u);
}
__device__ __forceinline__ float bflo(unsigned int p) { return __uint_as_float(p << 16); }
__device__ __forceinline__ float bfhi(unsigned int p) { return __uint_as_float(p & 0xffff0000u); }

// ---------------- pose (inline, redundant per thread) + transform ----------------
// grid 32 blocks (one per batch) x 1024 threads; store (x,y,z,|p|^2)
__global__ __launch_bounds__(1024) void k_prep(
    const float* __restrict__ p1, const float* __restrict__ p2,
    const float* __restrict__ scale, const float* __restrict__ rot,
    const float* __restrict__ tr,
    float4* __restrict__ p1to2, float4* __restrict__ p2to1) {
    int b = blockIdx.x;
    int t = threadIdx.x;
    float s = scale[b];
    float M[9];
#pragma unroll
    for (int i = 0; i < 9; ++i) M[i] = rot[b * 9 + i] * s;
    float t0 = tr[b * 3 + 0], t1 = tr[b * 3 + 1], t2 = tr[b * 3 + 2];
    float det = M[0] * (M[4] * M[8] - M[5] * M[7])
              - M[1] * (M[3] * M[8] - M[5] * M[6])
              + M[2] * (M[3] * M[7] - M[4] * M[6]);
    float id = 1.0f / det;
    float inv[9];
    inv[0] =  (M[4] * M[8] - M[5] * M[7]) * id;
    inv[1] = -(M[1] * M[8] - M[2] * M[7]) * id;
    inv[2] =  (M[1] * M[5] - M[2] * M[4]) * id;
    inv[3] = -(M[3] * M[8] - M[5] * M[6]) * id;
    inv[4] =  (M[0] * M[8] - M[2] * M[6]) * id;
    inv[5] = -(M[0] * M[5] - M[2] * M[3]) * id;
    inv[6] =  (M[3] * M[7] - M[4] * M[6]) * id;
    inv[7] = -(M[0] * M[7] - M[1] * M[6]) * id;
    inv[8] =  (M[0] * M[4] - M[1] * M[3]) * id;
    float u0 = -(inv[0] * t0 + inv[1] * t1 + inv[2] * t2);
    float u1 = -(inv[3] * t0 + inv[4] * t1 + inv[5] * t2);
    float u2 = -(inv[6] * t0 + inv[7] * t1 + inv[8] * t2);

    int idx = b * NP + t;
    float x = p1[idx * 3 + 0], y = p1[idx * 3 + 1], z = p1[idx * 3 + 2];
    float o0 = M[0] * x + M[1] * y + M[2] * z + t0;
    float o1 = M[3] * x + M[4] * y + M[5] * z + t1;
    float o2 = M[6] * x + M[7] * y + M[8] * z + t2;
    p1to2[idx] = make_float4(o0, o1, o2, o0 * o0 + o1 * o1 + o2 * o2);
    x = p2[idx * 3 + 0]; y = p2[idx * 3 + 1]; z = p2[idx * 3 + 2];
    o0 = inv[0] * x + inv[1] * y + inv[2] * z + u0;
    o1 = inv[3] * x + inv[4] * y + inv[5] * z + u1;
    o2 = inv[6] * x + inv[7] * y + inv[8] * z + u2;
    p2to1[idx] = make_float4(o0, o1, o2, o0 * o0 + o1 * o1 + o2 * o2);
}

// ---------------- the big fused pass over both assign matrices ----------------
// grid: 32 batches * 32 rowblocks = 1024 blocks, 256 threads (4 waves, 8 rows/wave).
// C/T column sums live in REGISTERS (16+16 per matrix per lane); flushed ONCE per
// block through LDS atomics (permuted layout idx = k*256 + 64*j + ln; the final
// sum(T*logC) is permutation-invariant since C and T share the layout).
__global__ __launch_bounds__(256, 2) void k_big(
    const float* __restrict__ am1, const float* __restrict__ am2,
    const float* __restrict__ pts1, const float* __restrict__ pts2,
    float4* __restrict__ p1in2, float4* __restrict__ p2in1,
    float* __restrict__ colC1, float* __restrict__ colT1,
    float* __restrict__ colC2, float* __restrict__ colT2,
    float* __restrict__ cosacc, float* __restrict__ acc) {
    const int b  = blockIdx.x >> 5;
    const int rb = blockIdx.x & 31;
    const int wv = threadIdx.x >> 6;
    const int ln = threadIdx.x & 63;
    const int row0 = rb * 32 + wv * 8;

    __shared__ float cacc[4][NP];
    {
        float* cf = (float*)cacc;
#pragma unroll
        for (int i = 0; i < 16; ++i) cf[threadIdx.x + 256 * i] = 0.f;
    }
    __syncthreads();

    // lane's 16 fixed columns: c = 256*j + 4*ln + k; points packed to bf16 pairs (48 regs)
    unsigned int pax[4][2], pay[4][2], paz[4][2];
    unsigned int pbx[4][2], pby[4][2], pbz[4][2];
#pragma unroll
    for (int j = 0; j < 4; ++j) {
        int base = (b * NP + 256 * j + 4 * ln) * 3;
        float4 t0 = *(const float4*)(pts2 + base);
        float4 t1 = *(const float4*)(pts2 + base + 4);
        float4 t2 = *(const float4*)(pts2 + base + 8);
        pax[j][0] = pkbf(t0.x, t0.w); pax[j][1] = pkbf(t1.z, t2.y);
        pay[j][0] = pkbf(t0.y, t1.x); pay[j][1] = pkbf(t1.w, t2.z);
        paz[j][0] = pkbf(t0.z, t1.y); paz[j][1] = pkbf(t2.x, t2.w);
        t0 = *(const float4*)(pts1 + base);
        t1 = *(const float4*)(pts1 + base + 4);
        t2 = *(const float4*)(pts1 + base + 8);
        pbx[j][0] = pkbf(t0.x, t0.w); pbx[j][1] = pkbf(t1.z, t2.y);
        pby[j][0] = pkbf(t0.y, t1.x); pby[j][1] = pkbf(t1.w, t2.z);
        pbz[j][0] = pkbf(t0.z, t1.y); pbz[j][1] = pkbf(t2.x, t2.w);
    }

    // register column accumulators (the round-1 dataflow, without the round-1 footprint)
    float C1[16], T1[16], C2[16], T2[16];
#pragma unroll
    for (int i = 0; i < 16; ++i) { C1[i] = 0.f; T1[i] = 0.f; C2[i] = 0.f; T2[i] = 0.f; }
    float dacc = 0.f, n1a = 0.f, n2a = 0.f, e2a = 0.f, sSa = 0.f;

    const float4* rA = (const float4*)(am1 + ((size_t)b * NP + row0) * NP);
    const float4* rB = (const float4*)(am2 + ((size_t)b * NP + row0) * NP);

#pragma unroll 1
    for (int r = 0; r < 8; ++r) {
        float4 a[4], c4[4];
#pragma unroll
        for (int j = 0; j < 4; ++j) {
            a[j]  = rA[(size_t)r * 256 + ln + 64 * j];
            c4[j] = rB[(size_t)r * 256 + ln + 64 * j];
        }
        // cos-loss partials on raw values
#pragma unroll
        for (int j = 0; j < 4; ++j) {
            float4 a0 = a[j], c0 = c4[j];
            dacc = fmaf(a0.x, c0.x, fmaf(a0.y, c0.y, fmaf(a0.z, c0.z, fmaf(a0.w, c0.w, dacc))));
            n1a  = fmaf(a0.x, a0.x, fmaf(a0.y, a0.y, fmaf(a0.z, a0.z, fmaf(a0.w, a0.w, n1a))));
            n2a  = fmaf(c0.x, c0.x, fmaf(c0.y, c0.y, fmaf(c0.z, c0.z, fmaf(c0.w, c0.w, n2a))));
        }
        // ---- matrix 1 ----
        {
            float R = 0.f, Su = 0.f, qx = 0.f, qy = 0.f, qz = 0.f;
#pragma unroll
            for (int j = 0; j < 4; ++j) {
                float4 v = a[j];
                float e0 = __expf(v.x), e1 = __expf(v.y), e2 = __expf(v.z), e3 = __expf(v.w);
                R += (e0 + e1) + (e2 + e3);
                Su = fmaf(e0, v.x, Su); Su = fmaf(e1, v.y, Su);
                Su = fmaf(e2, v.z, Su); Su = fmaf(e3, v.w, Su);
                qx = fmaf(e0, bflo(pax[j][0]), qx); qx = fmaf(e1, bfhi(pax[j][0]), qx);
                qx = fmaf(e2, bflo(pax[j][1]), qx); qx = fmaf(e3, bfhi(pax[j][1]), qx);
                qy = fmaf(e0, bflo(pay[j][0]), qy); qy = fmaf(e1, bfhi(pay[j][0]), qy);
                qy = fmaf(e2, bflo(pay[j][1]), qy); qy = fmaf(e3, bfhi(pay[j][1]), qy);
                qz = fmaf(e0, bflo(paz[j][0]), qz); qz = fmaf(e1, bfhi(paz[j][0]), qz);
                qz = fmaf(e2, bflo(paz[j][1]), qz); qz = fmaf(e3, bfhi(paz[j][1]), qz);
                C1[4 * j + 0] += e0; C1[4 * j + 1] += e1;
                C1[4 * j + 2] += e2; C1[4 * j + 3] += e3;
                a[j] = make_float4(e0, e1, e2, e3);
            }
#pragma unroll
            for (int m = 1; m < 64; m <<= 1) {
                R  += __shfl_xor(R, m);  Su += __shfl_xor(Su, m);
                qx += __shfl_xor(qx, m); qy += __shfl_xor(qy, m); qz += __shfl_xor(qz, m);
            }
            float inv = 1.0f / R;
#pragma unroll
            for (int j = 0; j < 4; ++j) {
                float4 e = a[j];
                T1[4 * j + 0] = fmaf(e.x, inv, T1[4 * j + 0]);
                T1[4 * j + 1] = fmaf(e.y, inv, T1[4 * j + 1]);
                T1[4 * j + 2] = fmaf(e.z, inv, T1[4 * j + 2]);
                T1[4 * j + 3] = fmaf(e.w, inv, T1[4 * j + 3]);
            }
            float S = Su * inv;
            if (ln == 0) {
                e2a += __logf(R) - S;
                sSa += S;
                float o0 = qx * inv, o1 = qy * inv, o2 = qz * inv;
                p1in2[b * NP + row0 + r] = make_float4(o0, o1, o2, o0 * o0 + o1 * o1 + o2 * o2);
            }
        }
        // ---- matrix 2 ----
        {
            float R = 0.f, Su = 0.f, qx = 0.f, qy = 0.f, qz = 0.f;
#pragma unroll
            for (int j = 0; j < 4; ++j) {
                float4 v = c4[j];
                float e0 = __expf(v.x), e1 = __expf(v.y), e2 = __expf(v.z), e3 = __expf(v.w);
                R += (e0 + e1) + (e2 + e3);
                Su = fmaf(e0, v.x, Su); Su = fmaf(e1, v.y, Su);
                Su = fmaf(e2, v.z, Su); Su = fmaf(e3, v.w, Su);
                qx = fmaf(e0, bflo(pbx[j][0]), qx); qx = fmaf(e1, bfhi(pbx[j][0]), qx);
                qx = fmaf(e2, bflo(pbx[j][1]), qx); qx = fmaf(e3, bfhi(pbx[j][1]), qx);
                qy = fmaf(e0, bflo(pby[j][0]), qy); qy = fmaf(e1, bfhi(pby[j][0]), qy);
                qy = fmaf(e2, bflo(pby[j][1]), qy); qy = fmaf(e3, bfhi(pby[j][1]), qy);
                qz = fmaf(e0, bflo(pbz[j][0]), qz); qz = fmaf(e1, bfhi(pbz[j][0]), qz);
                qz = fmaf(e2, bflo(pbz[j][1]), qz); qz = fmaf(e3, bfhi(pbz[j][1]), qz);
                C2[4 * j + 0] += e0; C2[4 * j + 1] += e1;
                C2[4 * j + 2] += e2; C2[4 * j + 3] += e3;
                c4[j] = make_float4(e0, e1, e2, e3);
            }
#pragma unroll
            for (int m = 1; m < 64; m <<= 1) {
                R  += __shfl_xor(R, m);  Su += __shfl_xor(Su, m);
                qx += __shfl_xor(qx, m); qy += __shfl_xor(qy, m); qz += __shfl_xor(qz, m);
            }
            float inv = 1.0f / R;
#pragma unroll
            for (int j = 0; j < 4; ++j) {
                float4 e = c4[j];
                T2[4 * j + 0] = fmaf(e.x, inv, T2[4 * j + 0]);
                T2[4 * j + 1] = fmaf(e.y, inv, T2[4 * j + 1]);
                T2[4 * j + 2] = fmaf(e.z, inv, T2[4 * j + 2]);
                T2[4 * j + 3] = fmaf(e.w, inv, T2[4 * j + 3]);
            }
            float S = Su * inv;
            if (ln == 0) {
                e2a += __logf(R) - S;
                sSa += S;
                float o0 = qx * inv, o1 = qy * inv, o2 = qz * inv;
                p2in1[b * NP + row0 + r] = make_float4(o0, o1, o2, o0 * o0 + o1 * o1 + o2 * o2);
            }
        }
    }

    // ---- block-level combine: ONE LDS atomic flush per lane (not per row) ----
    // permuted layout: (k, j, ln) -> idx = k*256 + 64*j + ln  (bank = ln%32, 2-way, free)
#pragma unroll
    for (int j = 0; j < 4; ++j) {
        int i0 = 64 * j + ln;
        atomicAdd(&cacc[0][0 * 256 + i0], C1[4 * j + 0]);
        atomicAdd(&cacc[0][1 * 256 + i0], C1[4 * j + 1]);
        atomicAdd(&cacc[0][2 * 256 + i0], C1[4 * j + 2]);
        atomicAdd(&cacc[0][3 * 256 + i0], C1[4 * j + 3]);
        atomicAdd(&cacc[1][0 * 256 + i0], T1[4 * j + 0]);
        atomicAdd(&cacc[1][1 * 256 + i0], T1[4 * j + 1]);
        atomicAdd(&cacc[1][2 * 256 + i0], T1[4 * j + 2]);
        atomicAdd(&cacc[1][3 * 256 + i0], T1[4 * j + 3]);
        atomicAdd(&cacc[2][0 * 256 + i0], C2[4 * j + 0]);
        atomicAdd(&cacc[2][1 * 256 + i0], C2[4 * j + 1]);
        atomicAdd(&cacc[2][2 * 256 + i0], C2[4 * j + 2]);
        atomicAdd(&cacc[2][3 * 256 + i0], C2[4 * j + 3]);
        atomicAdd(&cacc[3][0 * 256 + i0], T2[4 * j + 0]);
        atomicAdd(&cacc[3][1 * 256 + i0], T2[4 * j + 1]);
        atomicAdd(&cacc[3][2 * 256 + i0], T2[4 * j + 2]);
        atomicAdd(&cacc[3][3 * 256 + i0], T2[4 * j + 3]);
    }
    __syncthreads();
    // one coalesced global flush per block
#pragma unroll
    for (int qq = 0; qq < 4; ++qq) {
        int c = 256 * qq + threadIdx.x;
        atomicAdd(&colC1[b * NP + c], cacc[0][c]);
        atomicAdd(&colT1[b * NP + c], cacc[1][c]);
        atomicAdd(&colC2[b * NP + c], cacc[2][c]);
        atomicAdd(&colT2[b * NP + c], cacc[3][c]);
    }

#pragma unroll
    for (int m = 1; m < 64; m <<= 1) {
        dacc += __shfl_xor(dacc, m);
        n1a  += __shfl_xor(n1a, m);
        n2a  += __shfl_xor(n2a, m);
    }
    if (ln == 0) {
        atomicAdd(&cosacc[b], dacc);
        atomicAdd(&cosacc[32 + b], n1a);
        atomicAdd(&cosacc[64 + b], n2a);
        atomicAdd(&acc[0], e2a);
        atomicAdd(&acc[1], sSa);
    }
}

// ---------------- column finalize (T*logC) + correspondence loss ----------------
__global__ void k_tail(const float* __restrict__ colC1, const float* __restrict__ colT1,
                       const float* __restrict__ colC2, const float* __restrict__ colT2,
                       const float4* __restrict__ p1in2, const float4* __restrict__ p1to2,
                       const float4* __restrict__ p2in1, const float4* __restrict__ p2to1,
                       float* __restrict__ acc) {
    int idx = blockIdx.x * 256 + threadIdx.x;   // 65536
    float v;
    int i = idx;
    const float4* A; const float4* P;
    if (idx < 32768) {
        v = colT1[idx] * __logf(colC1[idx]);
        A = p1in2; P = p1to2;
    } else {
        int i2 = idx - 32768;
        v = colT2[i2] * __logf(colC2[i2]);
        A = p2in1; P = p2to1; i = i2;
    }
    float4 av = A[i], pv = P[i];
    float s = 0.f;
    float df;
    df = fabsf(av.x - pv.x); s += (df > 0.1f) ? (df - 0.05f) : (df * df * 5.0f);
    df = fabsf(av.y - pv.y); s += (df > 0.1f) ? (df - 0.05f) : (df * df * 5.0f);
    df = fabsf(av.z - pv.z); s += (df > 0.1f) ? (df - 0.05f) : (df * df * 5.0f);
#pragma unroll
    for (int m = 1; m < 64; m <<= 1) { v += __shfl_xor(v, m); s += __shfl_xor(s, m); }
    if ((threadIdx.x & 63) == 0) { atomicAdd(&acc[2], v); atomicAdd(&acc[3], s); }
}

// ---------------- chamfer + finalize (atomic ticket) ----------------
// min|x-y|^2 = max(|x|^2 + min_y(|y|^2 - 2 x.y), 0)
// grid 512 = pair(2)*dir(2)*b(32)*xquarter(4); 256 thr, 1 x/thread; y loop is
// wave-uniform -> scalar loads, no LDS, no cross-wave combine (fixes r3 bug).
__global__ __launch_bounds__(256) void k_cham(
    const float4* __restrict__ p1to2, const float4* __restrict__ p1in2,
    const float4* __restrict__ p2to1, const float4* __restrict__ p2in1,
    float* __restrict__ acc, const float* __restrict__ cosacc,
    unsigned int* __restrict__ tick, float* __restrict__ out) {
    int blk   = blockIdx.x;
    int xq    = blk & 3;
    int b     = (blk >> 2) & 31;
    int dir   = (blk >> 7) & 1;
    int pair  = blk >> 8;
    const float4* X; const float4* Y;
    if (pair == 0) { X = dir ? p1in2 : p1to2; Y = dir ? p1to2 : p1in2; }
    else           { X = dir ? p2in1 : p2to1; Y = dir ? p2to1 : p2in1; }
    int t = threadIdx.x;
    float4 xv = X[b * NP + xq * 256 + t];
    float nx = -2.0f * xv.x, ny = -2.0f * xv.y, nz = -2.0f * xv.z;
    float mn = 3.0e38f;
    const float4* yb = Y + b * NP;
#pragma unroll 4
    for (int o = 0; o < NP; ++o) {
        float4 yv = yb[o];                       // wave-uniform address
        mn = fminf(mn, fmaf(nx, yv.x, fmaf(ny, yv.y, fmaf(nz, yv.z, yv.w))));
    }
    float s = fmaxf(xv.w + mn, 0.f);
#pragma unroll
    for (int m = 1; m < 64; m <<= 1) s += __shfl_xor(s, m);
    if ((t & 63) == 0) atomicAdd(&acc[4], s);
    __threadfence();
    __syncthreads();
    if (t == 0) {
        unsigned int old = atomicAdd(tick, 1u);
        if (old == 511u) {          // last block finalizes
            const float invBN = 1.0f / 32768.0f;
            float a0 = __hip_atomic_load(&acc[0], __ATOMIC_RELAXED, __HIP_MEMORY_SCOPE_AGENT);
            float a1 = __hip_atomic_load(&acc[1], __ATOMIC_RELAXED, __HIP_MEMORY_SCOPE_AGENT);
            float a2 = __hip_atomic_load(&acc[2], __ATOMIC_RELAXED, __HIP_MEMORY_SCOPE_AGENT);
            float a3 = __hip_atomic_load(&acc[3], __ATOMIC_RELAXED, __HIP_MEMORY_SCOPE_AGENT);
            float a4 = __hip_atomic_load(&acc[4], __ATOMIC_RELAXED, __HIP_MEMORY_SCOPE_AGENT);
            float cosl = 0.f;
            for (int bb = 0; bb < 32; ++bb) {
                float dot = __hip_atomic_load(&cosacc[bb], __ATOMIC_RELAXED, __HIP_MEMORY_SCOPE_AGENT);
                float na  = __hip_atomic_load(&cosacc[32 + bb], __ATOMIC_RELAXED, __HIP_MEMORY_SCOPE_AGENT);
                float nb  = __hip_atomic_load(&cosacc[64 + bb], __ATOMIC_RELAXED, __HIP_MEMORY_SCOPE_AGENT);
                na = fmaxf(sqrtf(na), 1e-8f);
                nb = fmaxf(sqrtf(nb), 1e-8f);
                cosl += 1.0f - dot / (na * nb);
            }
            cosl *= (1.0f / 32.0f);
            float ent2 = 1e-4f * a0 * invBN;
            float ent1 = 1e-4f * (a2 - a1) * invBN;
            out[0] = a4 * invBN + a3 * invBN + ent2 + ent1 + cosl;
        }
    }
}

extern "C" void kernel_launch(void* const* d_in, const int* in_sizes, int n_in,
                              void* d_out, int out_size, void* d_ws, size_t ws_size,
                              hipStream_t stream) {
    const float* p1    = (const float*)d_in[0];
    const float* p2    = (const float*)d_in[1];
    const float* am1   = (const float*)d_in[2];
    const float* am2   = (const float*)d_in[3];
    const float* scale = (const float*)d_in[4];
    const float* rot   = (const float*)d_in[5];
    const float* tr    = (const float*)d_in[6];

    float* ws = (float*)d_ws;
    float* acc    = ws + OFF_ACC;
    float* cosacc = ws + OFF_COS;
    float* colC1  = ws + OFF_COLC1;
    float* colT1  = ws + OFF_COLT1;
    float* colC2  = ws + OFF_COLC2;
    float* colT2  = ws + OFF_COLT2;
    float4* p1to2 = (float4*)(ws + OFF_P1TO2);
    float4* p2to1 = (float4*)(ws + OFF_P2TO1);
    float4* p1in2 = (float4*)(ws + OFF_P1IN2);
    float4* p2in1 = (float4*)(ws + OFF_P2IN1);
    unsigned int* tick = (unsigned int*)(acc + 6);

    hipMemsetAsync(ws, 0, ZERO_FLOATS * sizeof(float), stream);

    k_prep<<<32, 1024, 0, stream>>>(p1, p2, scale, rot, tr, p1to2, p2to1);
    k_big<<<1024, 256, 0, stream>>>(am1, am2, p1, p2, p1in2, p2in1,
                                    colC1, colT1, colC2, colT2, cosacc, acc);
    k_tail<<<256, 256, 0, stream>>>(colC1, colT1, colC2, colT2,
                                    p1in2, p1to2, p2in1, p2to1, acc);
    k_cham<<<512, 256, 0, stream>>>(p1to2, p1in2, p2to1, p2in1,
                                    acc, cosacc, tick, (float*)d_out);
}